// Round 8
// baseline (445.350 us; speedup 1.0000x reference)
//
#include <hip/hip_runtime.h>
#include <hip/hip_bf16.h>
#include <math.h>

#define B_TOT 512
#define SEQ   179
#define EMB   256
#define HEADS 8
#define HD    32
#define LIN   720
#define EPSV  1e-5f

typedef __attribute__((ext_vector_type(8))) short bf16x8;
typedef __attribute__((ext_vector_type(4))) float f32x4;

__device__ __forceinline__ short f2bf(float f) {          // RNE f32->bf16 bits
    unsigned u = __float_as_uint(f);
    return (short)((u + 0x7fff + ((u >> 16) & 1)) >> 16);
}
__device__ __forceinline__ unsigned cvt_pk_bf16(float lo, float hi) {
    unsigned r;
    asm("v_cvt_pk_bf16_f32 %0, %1, %2" : "=v"(r) : "v"(lo), "v"(hi));
    return r;
}

// ---------------------------------------------------------------- PE table
__global__ void pe_kernel(float* __restrict__ pe) {
    int idx = blockIdx.x * 256 + threadIdx.x;
    if (idx >= SEQ * EMB) return;
    int s = idx / EMB, e = idx % EMB;
    int i = e >> 1;
    float dv  = expf((float)(2 * i) * (-9.210340371976184f / (float)EMB));
    float ang = (float)s * dv * ((float)EMB / (float)SEQ);
    pe[idx] = (e & 1) ? cosf(ang) : sinf(ang);
}

// ------------------------------------- f32 -> bf16 convert, 6 weights at once
__global__ void cvt6_kernel(const float* __restrict__ s0, const float* __restrict__ s1,
                            const float* __restrict__ s2, const float* __restrict__ s3,
                            const float* __restrict__ s4, const float* __restrict__ s5,
                            __hip_bfloat16* __restrict__ dst, int n) {
    int w = blockIdx.y;
    const float* src = (w == 0) ? s0 : (w == 1) ? s1 : (w == 2) ? s2
                     : (w == 3) ? s3 : (w == 4) ? s4 : s5;
    __hip_bfloat16* d = dst + (size_t)w * n;
    int i = (blockIdx.x * 256 + threadIdx.x) * 4;
    if (i < n) {
        float4 v = *reinterpret_cast<const float4*>(&src[i]);
        d[i + 0] = __float2bfloat16(v.x);
        d[i + 1] = __float2bfloat16(v.y);
        d[i + 2] = __float2bfloat16(v.z);
        d[i + 3] = __float2bfloat16(v.w);
    }
}

// ------------------------ conv(stride4,K8) + BN + ReLU + PE -> bf16 X
__global__ __launch_bounds__(256) void embed_kernel(
    const float* __restrict__ x, const float* __restrict__ cw,
    const float* __restrict__ cb, const float* __restrict__ g,
    const float* __restrict__ bb, const float* __restrict__ mean,
    const float* __restrict__ var, const float* __restrict__ pe,
    __hip_bfloat16* __restrict__ Xb)
{
    int bs = blockIdx.x;
    int b  = bs / SEQ, s = bs % SEQ;
    int e  = threadIdx.x;
    __shared__ float xin[8];
    if (threadIdx.x < 8) xin[threadIdx.x] = x[(size_t)b * LIN + s * 4 + threadIdx.x];
    __syncthreads();
    float acc = cb[e];
#pragma unroll
    for (int j = 0; j < 8; ++j) acc += xin[j] * cw[e * 8 + j];
    acc = (acc - mean[e]) * (g[e] * rsqrtf(var[e] + EPSV)) + bb[e];
    acc = fmaxf(acc, 0.f);
    Xb[(size_t)bs * EMB + e] = __float2bfloat16(acc + pe[s * EMB + e]);
}

// ---------------- MFMA bf16 GEMM: C[m,n] = sum_k A[m,k] * W[n,k], C in bf16
__global__ __launch_bounds__(256) void gemm_qkv_mfma(
    const __hip_bfloat16* __restrict__ A,    // [Mpad][256]
    const __hip_bfloat16* __restrict__ Wset, // [3][256][256]
    __hip_bfloat16* __restrict__ Q, __hip_bfloat16* __restrict__ K,
    __hip_bfloat16* __restrict__ V, int M)
{
    int by = blockIdx.y;                       // 0..5
    int wsel = by >> 1;
    const __hip_bfloat16* W = Wset + (size_t)wsel * EMB * EMB;
    __hip_bfloat16* C = (wsel == 0) ? Q : (wsel == 1 ? K : V);
    int nbase = (by & 1) * 128;
    int mbase = blockIdx.x * 128;

    __shared__ __hip_bfloat16 As[128][64];
    __shared__ __hip_bfloat16 Bs[128][64];

    int tid  = threadIdx.x;
    int wave = tid >> 6, lane = tid & 63;
    int wr = wave >> 1, wc = wave & 1;

    int r0   = tid >> 3;
    int srcs = (tid & 7) ^ (r0 & 7);
    const __hip_bfloat16* gA = A + (size_t)(mbase + r0) * EMB + srcs * 8;
    const __hip_bfloat16* gB = W + (size_t)(nbase + r0) * EMB + srcs * 8;

    f32x4 acc[4][4];
#pragma unroll
    for (int i = 0; i < 4; ++i)
#pragma unroll
        for (int j = 0; j < 4; ++j) acc[i][j] = (f32x4){0.f, 0.f, 0.f, 0.f};

    for (int kt = 0; kt < EMB; kt += 64) {
        if (kt) __syncthreads();
#pragma unroll
        for (int i = 0; i < 4; ++i) {
            __hip_bfloat16* l = &As[0][0] + i * 2048 + tid * 8;
            __builtin_amdgcn_global_load_lds(
                (const __attribute__((address_space(1))) void*)(gA + (size_t)i * 32 * EMB + kt),
                (__attribute__((address_space(3))) void*)l, 16, 0, 0);
        }
#pragma unroll
        for (int i = 0; i < 4; ++i) {
            __hip_bfloat16* l = &Bs[0][0] + i * 2048 + tid * 8;
            __builtin_amdgcn_global_load_lds(
                (const __attribute__((address_space(1))) void*)(gB + (size_t)i * 32 * EMB + kt),
                (__attribute__((address_space(3))) void*)l, 16, 0, 0);
        }
        asm volatile("s_waitcnt vmcnt(0)" ::: "memory");
        __syncthreads();

#pragma unroll
        for (int kk = 0; kk < 2; ++kk) {
            bf16x8 af[4], bfr[4];
            int sg = kk * 4 + (lane >> 4);
#pragma unroll
            for (int mi = 0; mi < 4; ++mi) {
                int row = wr * 64 + mi * 16 + (lane & 15);
                int sl  = sg ^ (row & 7);
                af[mi] = *reinterpret_cast<const bf16x8*>(&As[row][sl * 8]);
            }
#pragma unroll
            for (int ni = 0; ni < 4; ++ni) {
                int row = wc * 64 + ni * 16 + (lane & 15);
                int sl  = sg ^ (row & 7);
                bfr[ni] = *reinterpret_cast<const bf16x8*>(&Bs[row][sl * 8]);
            }
#pragma unroll
            for (int mi = 0; mi < 4; ++mi)
#pragma unroll
                for (int ni = 0; ni < 4; ++ni)
                    acc[mi][ni] = __builtin_amdgcn_mfma_f32_16x16x32_bf16(
                        af[mi], bfr[ni], acc[mi][ni], 0, 0, 0);
        }
    }

    int rg = lane >> 4, cli = lane & 15;
#pragma unroll
    for (int mi = 0; mi < 4; ++mi)
#pragma unroll
        for (int j = 0; j < 4; ++j) {
            int m = mbase + wr * 64 + mi * 16 + rg * 4 + j;
            if (m < M) {
#pragma unroll
                for (int ni = 0; ni < 4; ++ni)
                    C[(size_t)m * EMB + nbase + wc * 64 + ni * 16 + cli] =
                        __float2bfloat16(acc[mi][ni][j]);
            }
        }
}

// ---------------- MFMA flash attention v3: swapped QK^T (q lane-local),
// cvt_pk packed P writes, scalar lrow. Block per (b,h), 4 waves x 48 q-rows.
__global__ __launch_bounds__(256) void attn_mfma_kernel(
    const __hip_bfloat16* __restrict__ Qb, const __hip_bfloat16* __restrict__ Kb,
    const __hip_bfloat16* __restrict__ Vb, __hip_bfloat16* __restrict__ O)
{
    int bh = blockIdx.x;
    int b = bh >> 3, h = bh & 7;
    const size_t base = (size_t)b * SEQ * EMB + (size_t)h * HD;

    // K2: row = t>>1, slot = (t&1)*4 + d/8, phys = slot^(row&7)
    __shared__ short K2[96][64];          // 12288 B
    // Vt: row = d, slot = t>>3, phys = slot^(d&7)
    __shared__ short Vt[32][256];         // 16384 B
    // P2: per wave, row = q(16), t in [0,96), stride 104 (13x16B -> ~2-way)
    __shared__ short P2[4][16][104];      // 13312 B

    int tid  = threadIdx.x;
    int wave = tid >> 6, lane = tid & 63;
    int cl = lane & 15, rg = lane >> 4;

    // ---- stage K (swizzled b128) + V transposed (rotated scalar scatter)
    for (int u = tid; u < 192 * 4; u += 256) {
        int t = u >> 2, d0 = (u & 3) << 3;
        uint4 kv = make_uint4(0, 0, 0, 0), vv = make_uint4(0, 0, 0, 0);
        if (t < SEQ) {
            kv = *reinterpret_cast<const uint4*>(&Kb[base + (size_t)t * EMB + d0]);
            vv = *reinterpret_cast<const uint4*>(&Vb[base + (size_t)t * EMB + d0]);
        }
        int krow = t >> 1;
        int kphy = (((t & 1) * 4 + (d0 >> 3)) ^ (krow & 7));
        *reinterpret_cast<uint4*>(&K2[krow][kphy * 8]) = kv;

        const unsigned short* pv = reinterpret_cast<const unsigned short*>(&vv);
        int slot = t >> 3;
        int rot  = (u & 3) * 2;
#pragma unroll
        for (int k = 0; k < 8; ++k) {
            int i = (k + rot) & 7;          // d&7 varies across lanes per instr
            int d = d0 + i;
            Vt[d][(slot ^ i) * 8 + (t & 7)] = (short)pv[i];
        }
    }
    __syncthreads();

    // scale/SEQ * log2(e), for exp2
    const float csw2 = (0.0625f / (float)SEQ) * 1.4426950408889634f;

    for (int qt = 0; qt < 3; ++qt) {
        int qbase = wave * 48 + qt * 16;

        // Q fragment (B operand): col = cl -> q = qbase+cl, k(d) = rg*8..+7
        bf16x8 aq = {};
        int sq = qbase + cl;
        if (sq < SEQ)
            aq = *reinterpret_cast<const bf16x8*>(&Qb[base + (size_t)sq * EMB + rg * 8]);
        float sf = (float)sq;

        f32x4 o0 = {0.f, 0.f, 0.f, 0.f}, o1 = {0.f, 0.f, 0.f, 0.f};
        float lrow = 0.f;                 // row-sum for q = cl (partial over rg)

        for (int hh = 0; hh < 2; ++hh) {
            // ---- K^T Q: swapped operands -> C[row=t_loc][col=q_loc]
            // per lane: q = cl (fixed), t = tile*16 + rg*4 + j
            f32x4 st[6];
#pragma unroll
            for (int tl = 0; tl < 6; ++tl) {
                int t   = (hh * 6 + tl) * 16 + cl;   // A-frag row index uses cl
                int kr  = t >> 1;
                int kph = (((t & 1) * 4 + rg) ^ (kr & 7));
                bf16x8 kf = *reinterpret_cast<const bf16x8*>(&K2[kr][kph * 8]);
                st[tl] = __builtin_amdgcn_mfma_f32_16x16x32_bf16(
                    kf, aq, (f32x4){0.f, 0.f, 0.f, 0.f}, 0, 0, 0);
            }

            // ---- fused weight+exp+sum + packed P write (4 consecutive t/lane)
#pragma unroll
            for (int tl = 0; tl < 6; ++tl) {
                int tb = hh * 96 + tl * 16 + rg * 4;
                float d0 = sf - (float)tb;
                float p[4];
#pragma unroll
                for (int j = 0; j < 4; ++j)
                    p[j] = exp2f(st[tl][j] * (fabsf(d0 - (float)j) * csw2));
                if (hh == 1 && tl == 5) {            // only tile containing t>=SEQ
#pragma unroll
                    for (int j = 0; j < 4; ++j)
                        if (tb + j >= SEQ) p[j] = 0.f;
                }
                lrow += (p[0] + p[1]) + (p[2] + p[3]);
                uint2 pk;
                pk.x = cvt_pk_bf16(p[0], p[1]);
                pk.y = cvt_pk_bf16(p[2], p[3]);
                *reinterpret_cast<uint2*>(&P2[wave][cl][tl * 16 + rg * 4]) = pk;
            }
            asm volatile("s_waitcnt lgkmcnt(0)" ::: "memory"); // wave-local wr->rd

            // ---- PV for this half: 3 t-chunks of 32
#pragma unroll
            for (int tcl = 0; tcl < 3; ++tcl) {
                bf16x8 pa = *reinterpret_cast<const bf16x8*>(&P2[wave][cl][tcl * 32 + rg * 8]);
                int vsl = ((hh * 3 + tcl) * 4 + rg);
                int vp0 = (vsl ^ (cl & 7));
                bf16x8 b0 = *reinterpret_cast<const bf16x8*>(&Vt[cl][vp0 * 8]);
                bf16x8 b1 = *reinterpret_cast<const bf16x8*>(&Vt[cl + 16][vp0 * 8]);
                o0 = __builtin_amdgcn_mfma_f32_16x16x32_bf16(pa, b0, o0, 0, 0, 0);
                o1 = __builtin_amdgcn_mfma_f32_16x16x32_bf16(pa, b1, o1, 0, 0, 0);
            }
            asm volatile("s_waitcnt lgkmcnt(0)" ::: "memory"); // reads done before P reuse
        }

        // ---- full row sum for q=cl: reduce across the 4 rg-groups
        lrow += __shfl_xor(lrow, 16);
        lrow += __shfl_xor(lrow, 32);

        // ---- store bf16; row q = qbase + rg*4 + j needs lrow from lane rg*4+j
#pragma unroll
        for (int j = 0; j < 4; ++j) {
            int s = qbase + rg * 4 + j;
            if (s < SEQ) {
                float rl = 1.0f / __shfl(lrow, rg * 4 + j);
                __hip_bfloat16* op = &O[base + (size_t)s * EMB];
                op[cl]      = __float2bfloat16(o0[j] * rl);
                op[16 + cl] = __float2bfloat16(o1[j] * rl);
            }
        }
    }
}

// ---------------- row LayerNorm + PE: wave-per-row, 4 rows/block, bf16 io
__global__ __launch_bounds__(256) void ln_pe4_kernel(
    const __hip_bfloat16* __restrict__ X, const float* __restrict__ g,
    const float* __restrict__ bb, const float* __restrict__ pe,
    __hip_bfloat16* __restrict__ Xb, int M)
{
    int r = blockIdx.x * 4 + (threadIdx.x >> 6);
    if (r >= M) return;
    int lane = threadIdx.x & 63;
    int s = r % SEQ;
    int c0 = lane * 4;

    uint2 raw = *reinterpret_cast<const uint2*>(&X[(size_t)r * EMB + c0]);
    float v[4];
    v[0] = __uint_as_float((raw.x & 0xffffu) << 16);
    v[1] = __uint_as_float(raw.x & 0xffff0000u);
    v[2] = __uint_as_float((raw.y & 0xffffu) << 16);
    v[3] = __uint_as_float(raw.y & 0xffff0000u);

    float sum = v[0] + v[1] + v[2] + v[3];
    float sq  = v[0]*v[0] + v[1]*v[1] + v[2]*v[2] + v[3]*v[3];
#pragma unroll
    for (int off = 32; off > 0; off >>= 1) {
        sum += __shfl_xor(sum, off);
        sq  += __shfl_xor(sq,  off);
    }
    float mu  = sum * (1.0f / EMB);
    float var = sq * (1.0f / EMB) - mu * mu;
    float is  = rsqrtf(var + EPSV);

    float4 gv = *reinterpret_cast<const float4*>(&g[c0]);
    float4 bv = *reinterpret_cast<const float4*>(&bb[c0]);
    float4 pv = *reinterpret_cast<const float4*>(&pe[s * EMB + c0]);
    float y0 = (v[0] - mu) * is * gv.x + bv.x + pv.x;
    float y1 = (v[1] - mu) * is * gv.y + bv.y + pv.y;
    float y2 = (v[2] - mu) * is * gv.z + bv.z + pv.z;
    float y3 = (v[3] - mu) * is * gv.w + bv.w + pv.w;

    uint2 o;
    o.x = (unsigned short)f2bf(y0) | ((unsigned)(unsigned short)f2bf(y1) << 16);
    o.y = (unsigned short)f2bf(y2) | ((unsigned)(unsigned short)f2bf(y3) << 16);
    *reinterpret_cast<uint2*>(&Xb[(size_t)r * EMB + c0]) = o;
}

// ------- fused: LN(lnA2) -> LN(ln2) -> mean-pool over SEQ -> FC[10]
__global__ __launch_bounds__(256) void lnfc_kernel(
    const __hip_bfloat16* __restrict__ X,
    const float* __restrict__ g1, const float* __restrict__ b1,
    const float* __restrict__ g2, const float* __restrict__ b2,
    const float* __restrict__ ow, const float* __restrict__ ob,
    float* __restrict__ out)
{
    int b    = blockIdx.x;
    int tid  = threadIdx.x;
    int wave = tid >> 6, lane = tid & 63;

    float g1v[4], b1v[4], g2v[4], b2v[4], pooled[4];
#pragma unroll
    for (int j = 0; j < 4; ++j) {
        int c = lane + 64 * j;
        g1v[j] = g1[c]; b1v[j] = b1[c];
        g2v[j] = g2[c]; b2v[j] = b2[c];
        pooled[j] = 0.f;
    }

    for (int s = wave; s < SEQ; s += 4) {
        const __hip_bfloat16* row = &X[((size_t)b * SEQ + s) * EMB];
        float v[4];
#pragma unroll
        for (int j = 0; j < 4; ++j) v[j] = __bfloat162float(row[lane + 64 * j]);

        float sum = v[0] + v[1] + v[2] + v[3];
        float sq  = v[0]*v[0] + v[1]*v[1] + v[2]*v[2] + v[3]*v[3];
#pragma unroll
        for (int off = 32; off > 0; off >>= 1) {
            sum += __shfl_xor(sum, off);
            sq  += __shfl_xor(sq,  off);
        }
        float mu  = sum * (1.0f / EMB);
        float var = sq * (1.0f / EMB) - mu * mu;
        float is  = rsqrtf(var + EPSV);
        float y[4];
#pragma unroll
        for (int j = 0; j < 4; ++j) y[j] = (v[j] - mu) * is * g1v[j] + b1v[j];

        sum = y[0] + y[1] + y[2] + y[3];
        sq  = y[0]*y[0] + y[1]*y[1] + y[2]*y[2] + y[3]*y[3];
#pragma unroll
        for (int off = 32; off > 0; off >>= 1) {
            sum += __shfl_xor(sum, off);
            sq  += __shfl_xor(sq,  off);
        }
        mu  = sum * (1.0f / EMB);
        var = sq * (1.0f / EMB) - mu * mu;
        is  = rsqrtf(var + EPSV);
#pragma unroll
        for (int j = 0; j < 4; ++j) pooled[j] += (y[j] - mu) * is * g2v[j] + b2v[j];
    }

    __shared__ float pp[4][EMB];
#pragma unroll
    for (int j = 0; j < 4; ++j) pp[wave][lane + 64 * j] = pooled[j];
    __syncthreads();
    __shared__ float pool[EMB];
    pool[tid] = (pp[0][tid] + pp[1][tid] + pp[2][tid] + pp[3][tid]) * (1.0f / (float)SEQ);
    __syncthreads();
    if (tid < 10) {
        float o = ob[tid];
        for (int k = 0; k < EMB; ++k) o += pool[k] * ow[tid * EMB + k];
        out[b * 10 + tid] = o;
    }
}

// ---------------------------------------------------------------- launch
extern "C" void kernel_launch(void* const* d_in, const int* in_sizes, int n_in,
                              void* d_out, int out_size, void* d_ws, size_t ws_size,
                              hipStream_t stream)
{
    const float* x      = (const float*)d_in[0];
    const float* conv_w = (const float*)d_in[1];
    const float* conv_b = (const float*)d_in[2];
    const float* bn_g   = (const float*)d_in[3];
    const float* bn_b   = (const float*)d_in[4];
    const float* bn_m   = (const float*)d_in[5];
    const float* bn_v   = (const float*)d_in[6];
    const float* wq1    = (const float*)d_in[7];
    const float* wk1    = (const float*)d_in[8];
    const float* wv1    = (const float*)d_in[9];
    const float* lnA1_g = (const float*)d_in[10];
    const float* lnA1_b = (const float*)d_in[11];
    const float* wq2    = (const float*)d_in[12];
    const float* wk2    = (const float*)d_in[13];
    const float* wv2    = (const float*)d_in[14];
    const float* lnA2_g = (const float*)d_in[15];
    const float* lnA2_b = (const float*)d_in[16];
    const float* ln2_g  = (const float*)d_in[17];
    const float* ln2_b  = (const float*)d_in[18];
    const float* out_w  = (const float*)d_in[19];
    const float* out_b  = (const float*)d_in[20];
    float* out = (float*)d_out;

    const size_t peN = (size_t)SEQ * EMB;
    const size_t wN  = (size_t)EMB * EMB;

    int chunk = B_TOT;
    while (chunk > 1) {
        size_t M    = (size_t)chunk * SEQ;
        size_t Mpad = (M + 127) / 128 * 128;
        size_t need = peN * 4 + 6 * wN * 2 + (Mpad + 4 * M) * EMB * 2;
        if (need <= ws_size) break;
        chunk >>= 1;
    }
    size_t M    = (size_t)chunk * SEQ;
    size_t Mpad = (M + 127) / 128 * 128;

    float*          pe = (float*)d_ws;
    __hip_bfloat16* Wb = (__hip_bfloat16*)(pe + peN);
    __hip_bfloat16* Xb = Wb + 6 * wN;
    __hip_bfloat16* Ob = Xb + Mpad * EMB;
    __hip_bfloat16* Qb = Ob + M * EMB;
    __hip_bfloat16* Kb = Qb + M * EMB;
    __hip_bfloat16* Vb = Kb + M * EMB;

    pe_kernel<<<(SEQ * EMB + 255) / 256, 256, 0, stream>>>(pe);
    {
        dim3 cg((unsigned)(wN / 1024), 6);
        cvt6_kernel<<<cg, 256, 0, stream>>>(wq1, wk1, wv1, wq2, wk2, wv2, Wb, (int)wN);
    }

    for (int b0 = 0; b0 < B_TOT; b0 += chunk) {
        int Bc = chunk;
        int Mi = Bc * SEQ;
        dim3 ggrid((unsigned)(Mpad / 128), 6);

        embed_kernel<<<Bc * SEQ, 256, 0, stream>>>(
            x + (size_t)b0 * LIN, conv_w, conv_b, bn_g, bn_b, bn_m, bn_v, pe, Xb);

        // --- attention block 1 ---
        gemm_qkv_mfma<<<ggrid, 256, 0, stream>>>(Xb, Wb, Qb, Kb, Vb, Mi);
        attn_mfma_kernel<<<Bc * HEADS, 256, 0, stream>>>(Qb, Kb, Vb, Ob);
        ln_pe4_kernel<<<(Mi + 3) / 4, 256, 0, stream>>>(Ob, lnA1_g, lnA1_b, pe, Xb, Mi);

        // --- attention block 2 ---
        gemm_qkv_mfma<<<ggrid, 256, 0, stream>>>(Xb, Wb + 3 * wN, Qb, Kb, Vb, Mi);
        attn_mfma_kernel<<<Bc * HEADS, 256, 0, stream>>>(Qb, Kb, Vb, Ob);
        lnfc_kernel<<<Bc, 256, 0, stream>>>(Ob, lnA2_g, lnA2_b, ln2_g, ln2_b,
                                            out_w, out_b, out + (size_t)b0 * 10);
    }
}

// Round 9
// 443.394 us; speedup vs baseline: 1.0044x; 1.0044x over previous
//
#include <hip/hip_runtime.h>
#include <hip/hip_bf16.h>
#include <math.h>

#define B_TOT 512
#define SEQ   179
#define EMB   256
#define HEADS 8
#define HD    32
#define LIN   720
#define EPSV  1e-5f

typedef __attribute__((ext_vector_type(8))) short bf16x8;
typedef __attribute__((ext_vector_type(4))) float f32x4;

__device__ __forceinline__ short f2bf(float f) {          // RNE f32->bf16 bits
    unsigned u = __float_as_uint(f);
    return (short)((u + 0x7fff + ((u >> 16) & 1)) >> 16);
}
__device__ __forceinline__ unsigned cvt_pk_bf16(float lo, float hi) {
    unsigned r;
    asm("v_cvt_pk_bf16_f32 %0, %1, %2" : "=v"(r) : "v"(lo), "v"(hi));
    return r;
}

// ---------------------------------------------------------------- PE table
__global__ void pe_kernel(float* __restrict__ pe) {
    int idx = blockIdx.x * 256 + threadIdx.x;
    if (idx >= SEQ * EMB) return;
    int s = idx / EMB, e = idx % EMB;
    int i = e >> 1;
    float dv  = expf((float)(2 * i) * (-9.210340371976184f / (float)EMB));
    float ang = (float)s * dv * ((float)EMB / (float)SEQ);
    pe[idx] = (e & 1) ? cosf(ang) : sinf(ang);
}

// ------------------------------------- f32 -> bf16 convert, 6 weights at once
__global__ void cvt6_kernel(const float* __restrict__ s0, const float* __restrict__ s1,
                            const float* __restrict__ s2, const float* __restrict__ s3,
                            const float* __restrict__ s4, const float* __restrict__ s5,
                            __hip_bfloat16* __restrict__ dst, int n) {
    int w = blockIdx.y;
    const float* src = (w == 0) ? s0 : (w == 1) ? s1 : (w == 2) ? s2
                     : (w == 3) ? s3 : (w == 4) ? s4 : s5;
    __hip_bfloat16* d = dst + (size_t)w * n;
    int i = (blockIdx.x * 256 + threadIdx.x) * 4;
    if (i < n) {
        float4 v = *reinterpret_cast<const float4*>(&src[i]);
        d[i + 0] = __float2bfloat16(v.x);
        d[i + 1] = __float2bfloat16(v.y);
        d[i + 2] = __float2bfloat16(v.z);
        d[i + 3] = __float2bfloat16(v.w);
    }
}

// ------------------------ conv(stride4,K8) + BN + ReLU + PE -> bf16 X
__global__ __launch_bounds__(256) void embed_kernel(
    const float* __restrict__ x, const float* __restrict__ cw,
    const float* __restrict__ cb, const float* __restrict__ g,
    const float* __restrict__ bb, const float* __restrict__ mean,
    const float* __restrict__ var, const float* __restrict__ pe,
    __hip_bfloat16* __restrict__ Xb)
{
    int bs = blockIdx.x;
    int b  = bs / SEQ, s = bs % SEQ;
    int e  = threadIdx.x;
    __shared__ float xin[8];
    if (threadIdx.x < 8) xin[threadIdx.x] = x[(size_t)b * LIN + s * 4 + threadIdx.x];
    __syncthreads();
    float acc = cb[e];
#pragma unroll
    for (int j = 0; j < 8; ++j) acc += xin[j] * cw[e * 8 + j];
    acc = (acc - mean[e]) * (g[e] * rsqrtf(var[e] + EPSV)) + bb[e];
    acc = fmaxf(acc, 0.f);
    Xb[(size_t)bs * EMB + e] = __float2bfloat16(acc + pe[s * EMB + e]);
}

// ---------------- MFMA bf16 GEMM: C[m,n] = sum_k A[m,k] * W[n,k], C in bf16
__global__ __launch_bounds__(256) void gemm_qkv_mfma(
    const __hip_bfloat16* __restrict__ A,    // [Mpad][256]
    const __hip_bfloat16* __restrict__ Wset, // [3][256][256]
    __hip_bfloat16* __restrict__ Q, __hip_bfloat16* __restrict__ K,
    __hip_bfloat16* __restrict__ V, int M)
{
    int by = blockIdx.y;                       // 0..5
    int wsel = by >> 1;
    const __hip_bfloat16* W = Wset + (size_t)wsel * EMB * EMB;
    __hip_bfloat16* C = (wsel == 0) ? Q : (wsel == 1 ? K : V);
    int nbase = (by & 1) * 128;
    int mbase = blockIdx.x * 128;

    __shared__ __hip_bfloat16 As[128][64];
    __shared__ __hip_bfloat16 Bs[128][64];

    int tid  = threadIdx.x;
    int wave = tid >> 6, lane = tid & 63;
    int wr = wave >> 1, wc = wave & 1;

    int r0   = tid >> 3;
    int srcs = (tid & 7) ^ (r0 & 7);
    const __hip_bfloat16* gA = A + (size_t)(mbase + r0) * EMB + srcs * 8;
    const __hip_bfloat16* gB = W + (size_t)(nbase + r0) * EMB + srcs * 8;

    f32x4 acc[4][4];
#pragma unroll
    for (int i = 0; i < 4; ++i)
#pragma unroll
        for (int j = 0; j < 4; ++j) acc[i][j] = (f32x4){0.f, 0.f, 0.f, 0.f};

    for (int kt = 0; kt < EMB; kt += 64) {
        if (kt) __syncthreads();
#pragma unroll
        for (int i = 0; i < 4; ++i) {
            __hip_bfloat16* l = &As[0][0] + i * 2048 + tid * 8;
            __builtin_amdgcn_global_load_lds(
                (const __attribute__((address_space(1))) void*)(gA + (size_t)i * 32 * EMB + kt),
                (__attribute__((address_space(3))) void*)l, 16, 0, 0);
        }
#pragma unroll
        for (int i = 0; i < 4; ++i) {
            __hip_bfloat16* l = &Bs[0][0] + i * 2048 + tid * 8;
            __builtin_amdgcn_global_load_lds(
                (const __attribute__((address_space(1))) void*)(gB + (size_t)i * 32 * EMB + kt),
                (__attribute__((address_space(3))) void*)l, 16, 0, 0);
        }
        asm volatile("s_waitcnt vmcnt(0)" ::: "memory");
        __syncthreads();

#pragma unroll
        for (int kk = 0; kk < 2; ++kk) {
            bf16x8 af[4], bfr[4];
            int sg = kk * 4 + (lane >> 4);
#pragma unroll
            for (int mi = 0; mi < 4; ++mi) {
                int row = wr * 64 + mi * 16 + (lane & 15);
                int sl  = sg ^ (row & 7);
                af[mi] = *reinterpret_cast<const bf16x8*>(&As[row][sl * 8]);
            }
#pragma unroll
            for (int ni = 0; ni < 4; ++ni) {
                int row = wc * 64 + ni * 16 + (lane & 15);
                int sl  = sg ^ (row & 7);
                bfr[ni] = *reinterpret_cast<const bf16x8*>(&Bs[row][sl * 8]);
            }
#pragma unroll
            for (int mi = 0; mi < 4; ++mi)
#pragma unroll
                for (int ni = 0; ni < 4; ++ni)
                    acc[mi][ni] = __builtin_amdgcn_mfma_f32_16x16x32_bf16(
                        af[mi], bfr[ni], acc[mi][ni], 0, 0, 0);
        }
    }

    int rg = lane >> 4, cli = lane & 15;
#pragma unroll
    for (int mi = 0; mi < 4; ++mi)
#pragma unroll
        for (int j = 0; j < 4; ++j) {
            int m = mbase + wr * 64 + mi * 16 + rg * 4 + j;
            if (m < M) {
#pragma unroll
                for (int ni = 0; ni < 4; ++ni)
                    C[(size_t)m * EMB + nbase + wc * 64 + ni * 16 + cli] =
                        __float2bfloat16(acc[mi][ni][j]);
            }
        }
}

// ---------------- MFMA flash attention v3: swapped QK^T (q lane-local),
// cvt_pk packed P writes, scalar lrow. Block per (b,h), 4 waves x 48 q-rows.
__global__ __launch_bounds__(256) void attn_mfma_kernel(
    const __hip_bfloat16* __restrict__ Qb, const __hip_bfloat16* __restrict__ Kb,
    const __hip_bfloat16* __restrict__ Vb, __hip_bfloat16* __restrict__ O)
{
    int bh = blockIdx.x;
    int b = bh >> 3, h = bh & 7;
    const size_t base = (size_t)b * SEQ * EMB + (size_t)h * HD;

    // K2: row = t>>1, slot = (t&1)*4 + d/8, phys = slot^(row&7)
    __shared__ short K2[96][64];          // 12288 B
    // Vt: row = d, slot = t>>3, phys = slot^(d&7)
    __shared__ short Vt[32][256];         // 16384 B
    // P2: per wave, row = q(16), t in [0,96), stride 104 (13x16B -> ~2-way)
    __shared__ short P2[4][16][104];      // 13312 B

    int tid  = threadIdx.x;
    int wave = tid >> 6, lane = tid & 63;
    int cl = lane & 15, rg = lane >> 4;

    // ---- stage K (swizzled b128) + V transposed (rotated scalar scatter)
    for (int u = tid; u < 192 * 4; u += 256) {
        int t = u >> 2, d0 = (u & 3) << 3;
        uint4 kv = make_uint4(0, 0, 0, 0), vv = make_uint4(0, 0, 0, 0);
        if (t < SEQ) {
            kv = *reinterpret_cast<const uint4*>(&Kb[base + (size_t)t * EMB + d0]);
            vv = *reinterpret_cast<const uint4*>(&Vb[base + (size_t)t * EMB + d0]);
        }
        int krow = t >> 1;
        int kphy = (((t & 1) * 4 + (d0 >> 3)) ^ (krow & 7));
        *reinterpret_cast<uint4*>(&K2[krow][kphy * 8]) = kv;

        const unsigned short* pv = reinterpret_cast<const unsigned short*>(&vv);
        int slot = t >> 3;
        int rot  = (u & 3) * 2;
#pragma unroll
        for (int k = 0; k < 8; ++k) {
            int i = (k + rot) & 7;          // d&7 varies across lanes per instr
            int d = d0 + i;
            Vt[d][(slot ^ i) * 8 + (t & 7)] = (short)pv[i];
        }
    }
    __syncthreads();

    // scale/SEQ * log2(e), for exp2
    const float csw2 = (0.0625f / (float)SEQ) * 1.4426950408889634f;

    for (int qt = 0; qt < 3; ++qt) {
        int qbase = wave * 48 + qt * 16;

        // Q fragment (B operand): col = cl -> q = qbase+cl, k(d) = rg*8..+7
        bf16x8 aq = {};
        int sq = qbase + cl;
        if (sq < SEQ)
            aq = *reinterpret_cast<const bf16x8*>(&Qb[base + (size_t)sq * EMB + rg * 8]);
        float sf = (float)sq;

        f32x4 o0 = {0.f, 0.f, 0.f, 0.f}, o1 = {0.f, 0.f, 0.f, 0.f};
        float lrow = 0.f;                 // row-sum for q = cl (partial over rg)

        for (int hh = 0; hh < 2; ++hh) {
            // ---- K^T Q: swapped operands -> C[row=t_loc][col=q_loc]
            // per lane: q = cl (fixed), t = tile*16 + rg*4 + j
            f32x4 st[6];
#pragma unroll
            for (int tl = 0; tl < 6; ++tl) {
                int t   = (hh * 6 + tl) * 16 + cl;   // A-frag row index uses cl
                int kr  = t >> 1;
                int kph = (((t & 1) * 4 + rg) ^ (kr & 7));
                bf16x8 kf = *reinterpret_cast<const bf16x8*>(&K2[kr][kph * 8]);
                st[tl] = __builtin_amdgcn_mfma_f32_16x16x32_bf16(
                    kf, aq, (f32x4){0.f, 0.f, 0.f, 0.f}, 0, 0, 0);
            }

            // ---- fused weight+exp+sum + packed P write (4 consecutive t/lane)
#pragma unroll
            for (int tl = 0; tl < 6; ++tl) {
                int tb = hh * 96 + tl * 16 + rg * 4;
                float d0 = sf - (float)tb;
                float p[4];
#pragma unroll
                for (int j = 0; j < 4; ++j)
                    p[j] = exp2f(st[tl][j] * (fabsf(d0 - (float)j) * csw2));
                if (hh == 1 && tl == 5) {            // only tile containing t>=SEQ
#pragma unroll
                    for (int j = 0; j < 4; ++j)
                        if (tb + j >= SEQ) p[j] = 0.f;
                }
                lrow += (p[0] + p[1]) + (p[2] + p[3]);
                uint2 pk;
                pk.x = cvt_pk_bf16(p[0], p[1]);
                pk.y = cvt_pk_bf16(p[2], p[3]);
                *reinterpret_cast<uint2*>(&P2[wave][cl][tl * 16 + rg * 4]) = pk;
            }
            asm volatile("s_waitcnt lgkmcnt(0)" ::: "memory"); // wave-local wr->rd

            // ---- PV for this half: 3 t-chunks of 32
#pragma unroll
            for (int tcl = 0; tcl < 3; ++tcl) {
                bf16x8 pa = *reinterpret_cast<const bf16x8*>(&P2[wave][cl][tcl * 32 + rg * 8]);
                int vsl = ((hh * 3 + tcl) * 4 + rg);
                int vp0 = (vsl ^ (cl & 7));
                bf16x8 b0 = *reinterpret_cast<const bf16x8*>(&Vt[cl][vp0 * 8]);
                bf16x8 b1 = *reinterpret_cast<const bf16x8*>(&Vt[cl + 16][vp0 * 8]);
                o0 = __builtin_amdgcn_mfma_f32_16x16x32_bf16(pa, b0, o0, 0, 0, 0);
                o1 = __builtin_amdgcn_mfma_f32_16x16x32_bf16(pa, b1, o1, 0, 0, 0);
            }
            asm volatile("s_waitcnt lgkmcnt(0)" ::: "memory"); // reads done before P reuse
        }

        // ---- full row sum for q=cl: reduce across the 4 rg-groups
        lrow += __shfl_xor(lrow, 16);
        lrow += __shfl_xor(lrow, 32);

        // ---- store bf16; row q = qbase + rg*4 + j needs lrow from lane rg*4+j
#pragma unroll
        for (int j = 0; j < 4; ++j) {
            int s = qbase + rg * 4 + j;
            if (s < SEQ) {
                float rl = 1.0f / __shfl(lrow, rg * 4 + j);
                __hip_bfloat16* op = &O[base + (size_t)s * EMB];
                op[cl]      = __float2bfloat16(o0[j] * rl);
                op[16 + cl] = __float2bfloat16(o1[j] * rl);
            }
        }
    }
}

// ---------------- row LayerNorm + PE: wave-per-row, 4 rows/block, bf16 io
__global__ __launch_bounds__(256) void ln_pe4_kernel(
    const __hip_bfloat16* __restrict__ X, const float* __restrict__ g,
    const float* __restrict__ bb, const float* __restrict__ pe,
    __hip_bfloat16* __restrict__ Xb, int M)
{
    int r = blockIdx.x * 4 + (threadIdx.x >> 6);
    if (r >= M) return;
    int lane = threadIdx.x & 63;
    int s = r % SEQ;
    int c0 = lane * 4;

    uint2 raw = *reinterpret_cast<const uint2*>(&X[(size_t)r * EMB + c0]);
    float v[4];
    v[0] = __uint_as_float((raw.x & 0xffffu) << 16);
    v[1] = __uint_as_float(raw.x & 0xffff0000u);
    v[2] = __uint_as_float((raw.y & 0xffffu) << 16);
    v[3] = __uint_as_float(raw.y & 0xffff0000u);

    float sum = v[0] + v[1] + v[2] + v[3];
    float sq  = v[0]*v[0] + v[1]*v[1] + v[2]*v[2] + v[3]*v[3];
#pragma unroll
    for (int off = 32; off > 0; off >>= 1) {
        sum += __shfl_xor(sum, off);
        sq  += __shfl_xor(sq,  off);
    }
    float mu  = sum * (1.0f / EMB);
    float var = sq * (1.0f / EMB) - mu * mu;
    float is  = rsqrtf(var + EPSV);

    float4 gv = *reinterpret_cast<const float4*>(&g[c0]);
    float4 bv = *reinterpret_cast<const float4*>(&bb[c0]);
    float4 pv = *reinterpret_cast<const float4*>(&pe[s * EMB + c0]);
    float y0 = (v[0] - mu) * is * gv.x + bv.x + pv.x;
    float y1 = (v[1] - mu) * is * gv.y + bv.y + pv.y;
    float y2 = (v[2] - mu) * is * gv.z + bv.z + pv.z;
    float y3 = (v[3] - mu) * is * gv.w + bv.w + pv.w;

    uint2 o;
    o.x = (unsigned short)f2bf(y0) | ((unsigned)(unsigned short)f2bf(y1) << 16);
    o.y = (unsigned short)f2bf(y2) | ((unsigned)(unsigned short)f2bf(y3) << 16);
    *reinterpret_cast<uint2*>(&Xb[(size_t)r * EMB + c0]) = o;
}

// ------- fused: LN(lnA2) -> LN(ln2) -> mean-pool over SEQ -> FC[10]
__global__ __launch_bounds__(256) void lnfc_kernel(
    const __hip_bfloat16* __restrict__ X,
    const float* __restrict__ g1, const float* __restrict__ b1,
    const float* __restrict__ g2, const float* __restrict__ b2,
    const float* __restrict__ ow, const float* __restrict__ ob,
    float* __restrict__ out)
{
    int b    = blockIdx.x;
    int tid  = threadIdx.x;
    int wave = tid >> 6, lane = tid & 63;

    float g1v[4], b1v[4], g2v[4], b2v[4], pooled[4];
#pragma unroll
    for (int j = 0; j < 4; ++j) {
        int c = lane + 64 * j;
        g1v[j] = g1[c]; b1v[j] = b1[c];
        g2v[j] = g2[c]; b2v[j] = b2[c];
        pooled[j] = 0.f;
    }

    for (int s = wave; s < SEQ; s += 4) {
        const __hip_bfloat16* row = &X[((size_t)b * SEQ + s) * EMB];
        float v[4];
#pragma unroll
        for (int j = 0; j < 4; ++j) v[j] = __bfloat162float(row[lane + 64 * j]);

        float sum = v[0] + v[1] + v[2] + v[3];
        float sq  = v[0]*v[0] + v[1]*v[1] + v[2]*v[2] + v[3]*v[3];
#pragma unroll
        for (int off = 32; off > 0; off >>= 1) {
            sum += __shfl_xor(sum, off);
            sq  += __shfl_xor(sq,  off);
        }
        float mu  = sum * (1.0f / EMB);
        float var = sq * (1.0f / EMB) - mu * mu;
        float is  = rsqrtf(var + EPSV);
        float y[4];
#pragma unroll
        for (int j = 0; j < 4; ++j) y[j] = (v[j] - mu) * is * g1v[j] + b1v[j];

        sum = y[0] + y[1] + y[2] + y[3];
        sq  = y[0]*y[0] + y[1]*y[1] + y[2]*y[2] + y[3]*y[3];
#pragma unroll
        for (int off = 32; off > 0; off >>= 1) {
            sum += __shfl_xor(sum, off);
            sq  += __shfl_xor(sq,  off);
        }
        mu  = sum * (1.0f / EMB);
        var = sq * (1.0f / EMB) - mu * mu;
        is  = rsqrtf(var + EPSV);
#pragma unroll
        for (int j = 0; j < 4; ++j) pooled[j] += (y[j] - mu) * is * g2v[j] + b2v[j];
    }

    __shared__ float pp[4][EMB];
#pragma unroll
    for (int j = 0; j < 4; ++j) pp[wave][lane + 64 * j] = pooled[j];
    __syncthreads();
    __shared__ float pool[EMB];
    pool[tid] = (pp[0][tid] + pp[1][tid] + pp[2][tid] + pp[3][tid]) * (1.0f / (float)SEQ);
    __syncthreads();
    if (tid < 10) {
        float o = ob[tid];
        for (int k = 0; k < EMB; ++k) o += pool[k] * ow[tid * EMB + k];
        out[b * 10 + tid] = o;
    }
}

// ---------------------------------------------------------------- launch
extern "C" void kernel_launch(void* const* d_in, const int* in_sizes, int n_in,
                              void* d_out, int out_size, void* d_ws, size_t ws_size,
                              hipStream_t stream)
{
    const float* x      = (const float*)d_in[0];
    const float* conv_w = (const float*)d_in[1];
    const float* conv_b = (const float*)d_in[2];
    const float* bn_g   = (const float*)d_in[3];
    const float* bn_b   = (const float*)d_in[4];
    const float* bn_m   = (const float*)d_in[5];
    const float* bn_v   = (const float*)d_in[6];
    const float* wq1    = (const float*)d_in[7];
    const float* wk1    = (const float*)d_in[8];
    const float* wv1    = (const float*)d_in[9];
    const float* lnA1_g = (const float*)d_in[10];
    const float* lnA1_b = (const float*)d_in[11];
    const float* wq2    = (const float*)d_in[12];
    const float* wk2    = (const float*)d_in[13];
    const float* wv2    = (const float*)d_in[14];
    const float* lnA2_g = (const float*)d_in[15];
    const float* lnA2_b = (const float*)d_in[16];
    const float* ln2_g  = (const float*)d_in[17];
    const float* ln2_b  = (const float*)d_in[18];
    const float* out_w  = (const float*)d_in[19];
    const float* out_b  = (const float*)d_in[20];
    float* out = (float*)d_out;

    const size_t peN = (size_t)SEQ * EMB;
    const size_t wN  = (size_t)EMB * EMB;

    int chunk = B_TOT;
    while (chunk > 1) {
        size_t M    = (size_t)chunk * SEQ;
        size_t Mpad = (M + 127) / 128 * 128;
        size_t need = peN * 4 + 6 * wN * 2 + (Mpad + 4 * M) * EMB * 2;
        if (need <= ws_size) break;
        chunk >>= 1;
    }
    size_t M    = (size_t)chunk * SEQ;
    size_t Mpad = (M + 127) / 128 * 128;

    float*          pe = (float*)d_ws;
    __hip_bfloat16* Wb = (__hip_bfloat16*)(pe + peN);
    __hip_bfloat16* Xb = Wb + 6 * wN;
    __hip_bfloat16* Ob = Xb + Mpad * EMB;
    __hip_bfloat16* Qb = Ob + M * EMB;
    __hip_bfloat16* Kb = Qb + M * EMB;
    __hip_bfloat16* Vb = Kb + M * EMB;

    pe_kernel<<<(SEQ * EMB + 255) / 256, 256, 0, stream>>>(pe);
    {
        dim3 cg((unsigned)(wN / 1024), 6);
        cvt6_kernel<<<cg, 256, 0, stream>>>(wq1, wk1, wv1, wq2, wk2, wv2, Wb, (int)wN);
    }

    for (int b0 = 0; b0 < B_TOT; b0 += chunk) {
        int Bc = chunk;
        int Mi = Bc * SEQ;
        dim3 ggrid((unsigned)(Mpad / 128), 6);

        embed_kernel<<<Bc * SEQ, 256, 0, stream>>>(
            x + (size_t)b0 * LIN, conv_w, conv_b, bn_g, bn_b, bn_m, bn_v, pe, Xb);

        // --- attention block 1 ---
        gemm_qkv_mfma<<<ggrid, 256, 0, stream>>>(Xb, Wb, Qb, Kb, Vb, Mi);
        attn_mfma_kernel<<<Bc * HEADS, 256, 0, stream>>>(Qb, Kb, Vb, Ob);
        ln_pe4_kernel<<<(Mi + 3) / 4, 256, 0, stream>>>(Ob, lnA1_g, lnA1_b, pe, Xb, Mi);

        // --- attention block 2 ---
        gemm_qkv_mfma<<<ggrid, 256, 0, stream>>>(Xb, Wb + 3 * wN, Qb, Kb, Vb, Mi);
        attn_mfma_kernel<<<Bc * HEADS, 256, 0, stream>>>(Qb, Kb, Vb, Ob);
        lnfc_kernel<<<Bc, 256, 0, stream>>>(Ob, lnA2_g, lnA2_b, ln2_g, ln2_b,
                                            out_w, out_b, out + (size_t)b0 * 10);
    }
}